// Round 2
// baseline (240.109 us; speedup 1.0000x reference)
//
#include <hip/hip_runtime.h>
#include <hip/hip_bf16.h>

typedef __bf16 bf16;
typedef __bf16 bf16x4 __attribute__((ext_vector_type(4)));
typedef __bf16 bf16x8 __attribute__((ext_vector_type(8)));
typedef float  f32x4  __attribute__((ext_vector_type(4)));

#define MFMA16(a, b, c) __builtin_amdgcn_mfma_f32_16x16x32_bf16((a), (b), (c), 0, 0, 0)

// Problem constants
#define BATCH 4
#define TOK   1024
#define DIM   1024
#define HEADS 16
#define HD    64
#define MTOT  (BATCH * TOK)   // 4096

// ---------------------------------------------------------------------------
// Kernel 1: QKV projection. Y = X @ W.T with 3-term bf16 split (fp32-grade).
// mode 0: Q (+RoPE, *1/8) -> (bh, n, d) bf16
// mode 1: K (+RoPE)       -> (bh, n, d) bf16
// mode 2: V               -> (bh, d, n) bf16 (transposed for PV B-operand)
// Tile 128x128, BK=32, 4 waves, each wave 64x64 (4x4 frags of 16x16x32).
// ---------------------------------------------------------------------------
__global__ __launch_bounds__(256) void k_qkv(
    const float* __restrict__ X,
    const float* __restrict__ Wq, const float* __restrict__ Wk, const float* __restrict__ Wv,
    const float* __restrict__ cosT, const float* __restrict__ sinT,
    bf16* __restrict__ qout, bf16* __restrict__ kout, bf16* __restrict__ vout)
{
    __shared__ bf16 Ah[128][40];
    __shared__ bf16 Al[128][40];
    __shared__ bf16 Bh[128][40];
    __shared__ bf16 Bl[128][40];

    const int mode = blockIdx.z;
    const float* W = (mode == 0) ? Wq : (mode == 1) ? Wk : Wv;

    const int nt = blockIdx.x;   // 0..7  (N tiles of 128)
    const int mt = blockIdx.y;   // 0..31 (M tiles of 128)
    const int t = threadIdx.x;
    const int lane = t & 63;
    const int w = t >> 6;
    const int wr = w >> 1, wc = w & 1;

    f32x4 zero = {0.f, 0.f, 0.f, 0.f};
    f32x4 acc[4][4];
    #pragma unroll
    for (int m = 0; m < 4; m++)
        #pragma unroll
        for (int n = 0; n < 4; n++) acc[m][n] = zero;

    // staging map: thread covers row sr, 16 floats starting at col sc
    const int sr = t >> 1, sc = (t & 1) * 16;
    const float* xs = X + (size_t)(mt * 128 + sr) * DIM + sc;
    const float* ws = W + (size_t)(nt * 128 + sr) * DIM + sc;

    for (int k0 = 0; k0 < DIM; k0 += 32) {
        __syncthreads();
        #pragma unroll
        for (int i = 0; i < 4; i++) {
            f32x4 vx = *(const f32x4*)(xs + k0 + i * 4);
            f32x4 vw = *(const f32x4*)(ws + k0 + i * 4);
            bf16x4 xh, xl, wh, wl;
            #pragma unroll
            for (int j = 0; j < 4; j++) {
                bf16 h = (bf16)vx[j]; xh[j] = h; xl[j] = (bf16)(vx[j] - (float)h);
                bf16 g = (bf16)vw[j]; wh[j] = g; wl[j] = (bf16)(vw[j] - (float)g);
            }
            *(bf16x4*)&Ah[sr][sc + i * 4] = xh;
            *(bf16x4*)&Al[sr][sc + i * 4] = xl;
            *(bf16x4*)&Bh[sr][sc + i * 4] = wh;
            *(bf16x4*)&Bl[sr][sc + i * 4] = wl;
        }
        __syncthreads();

        const int kq = (lane >> 4) * 8;
        bf16x8 ah[4], al[4], bh[4], bl[4];
        #pragma unroll
        for (int m = 0; m < 4; m++) {
            int r = wr * 64 + m * 16 + (lane & 15);
            ah[m] = *(const bf16x8*)&Ah[r][kq];
            al[m] = *(const bf16x8*)&Al[r][kq];
        }
        #pragma unroll
        for (int n = 0; n < 4; n++) {
            int r = wc * 64 + n * 16 + (lane & 15);
            bh[n] = *(const bf16x8*)&Bh[r][kq];
            bl[n] = *(const bf16x8*)&Bl[r][kq];
        }
        #pragma unroll
        for (int m = 0; m < 4; m++)
            #pragma unroll
            for (int n = 0; n < 4; n++) {
                acc[m][n] = MFMA16(ah[m], bh[n], acc[m][n]);
                acc[m][n] = MFMA16(al[m], bh[n], acc[m][n]);
                acc[m][n] = MFMA16(ah[m], bl[n], acc[m][n]);
            }
    }

    // Epilogue
    #pragma unroll
    for (int m = 0; m < 4; m++) {
        #pragma unroll
        for (int n = 0; n < 4; n++) {
            const int grow0 = mt * 128 + wr * 64 + m * 16 + (lane >> 4) * 4; // 4-aligned
            const int gcol  = nt * 128 + wc * 64 + n * 16 + (lane & 15);
            const int b = grow0 >> 10;
            const int h = gcol >> 6, d = gcol & 63;
            if (mode == 2) {
                // V: store transposed (bh, d, n); rows grow0..+3 are contiguous n.
                bf16x4 pk;
                #pragma unroll
                for (int r = 0; r < 4; r++) pk[r] = (bf16)acc[m][n][r];
                *(bf16x4*)&vout[((size_t)((b * HEADS + h) * HD + d)) * TOK + (grow0 & (TOK - 1))] = pk;
            } else {
                const int a = d >> 5, p = (d >> 1) & 15;
                const bool even = (d & 1) == 0;
                bf16* dst = (mode == 0) ? qout : kout;
                #pragma unroll
                for (int r = 0; r < 4; r++) {
                    float v = acc[m][n][r];
                    float pr = __shfl_xor(v, 1, 64);  // pair partner (col ^ 1)
                    int ntok = (grow0 & (TOK - 1)) + r;
                    float c = cosT[ntok * 32 + a * 16 + p];
                    float s = sinT[ntok * 32 + a * 16 + p];
                    float res = even ? (c * v - s * pr) : (s * pr + c * v);
                    if (mode == 0) res *= 0.125f;  // 1/sqrt(64)
                    dst[((size_t)(b * HEADS + h) * TOK + ntok) * HD + d] = (bf16)res;
                }
            }
        }
    }
}

// ---------------------------------------------------------------------------
// Kernel 2: flash-style attention per (b,h). 4 waves x 16 q-rows = 64 q/block.
// K-tiles of 128 keys, online softmax, PV via LDS-staged P and transposed V.
// ---------------------------------------------------------------------------
__global__ __launch_bounds__(256) void k_attn(
    const bf16* __restrict__ Q, const bf16* __restrict__ K,
    const bf16* __restrict__ Vt, bf16* __restrict__ O)
{
    __shared__ bf16 Ks[128][72];   // keys x d   (+8 pad)
    __shared__ bf16 Vs[64][136];   // d x keys   (+8 pad)
    __shared__ bf16 Ps[64][136];   // q x keys   (+8 pad)

    const int qt = blockIdx.x;   // 0..15
    const int bh = blockIdx.y;   // 0..63
    const int t = threadIdx.x;
    const int lane = t & 63;
    const int w = t >> 6;
    const int kq = (lane >> 4) * 8;

    // Q fragments in registers (16 q-rows per wave, d=64 -> 2 frags)
    const int qrow = qt * 64 + w * 16 + (lane & 15);
    const bf16* qp = Q + ((size_t)bh * TOK + qrow) * HD + kq;
    bf16x8 qf0 = *(const bf16x8*)qp;
    bf16x8 qf1 = *(const bf16x8*)(qp + 32);

    float m_r[4], l_r[4];
    f32x4 zero = {0.f, 0.f, 0.f, 0.f};
    f32x4 o_[4];
    #pragma unroll
    for (int r = 0; r < 4; r++) { m_r[r] = -1e30f; l_r[r] = 0.f; }
    #pragma unroll
    for (int dt = 0; dt < 4; dt++) o_[dt] = zero;

    for (int kt = 0; kt < 8; kt++) {
        __syncthreads();
        // stage K (128x64) and Vt (64x128) tiles: 1024 16B-chunks EACH.
        #pragma unroll
        for (int i = 0; i < 4; i++) {
            int j = i * 256 + t;               // 0..1023, coalesced in t
            int krow = j >> 3, kcol = (j & 7) * 8;
            *(bf16x8*)&Ks[krow][kcol] =
                *(const bf16x8*)(K + ((size_t)bh * TOK + kt * 128 + krow) * HD + kcol);
            int vrow = j >> 4, vcol = (j & 15) * 8;
            *(bf16x8*)&Vs[vrow][vcol] =
                *(const bf16x8*)(Vt + ((size_t)bh * HD + vrow) * TOK + kt * 128 + vcol);
        }
        __syncthreads();

        // S = (Q/8) K^T : 16 x 128 per wave
        f32x4 s[8];
        #pragma unroll
        for (int ct = 0; ct < 8; ct++) s[ct] = zero;
        #pragma unroll
        for (int ct = 0; ct < 8; ct++) {
            bf16x8 kf0 = *(const bf16x8*)&Ks[ct * 16 + (lane & 15)][kq];
            bf16x8 kf1 = *(const bf16x8*)&Ks[ct * 16 + (lane & 15)][32 + kq];
            s[ct] = MFMA16(qf0, kf0, s[ct]);
            s[ct] = MFMA16(qf1, kf1, s[ct]);
        }

        // online softmax per q-row (4 rows per lane)
        const int prow = w * 16 + (lane >> 4) * 4;
        #pragma unroll
        for (int r = 0; r < 4; r++) {
            float tmax = s[0][r];
            #pragma unroll
            for (int ct = 1; ct < 8; ct++) tmax = fmaxf(tmax, s[ct][r]);
            #pragma unroll
            for (int d2 = 1; d2 < 16; d2 <<= 1) tmax = fmaxf(tmax, __shfl_xor(tmax, d2, 64));
            float mnew = fmaxf(m_r[r], tmax);
            float scale = __expf(m_r[r] - mnew);
            m_r[r] = mnew;
            float rsum = 0.f;
            #pragma unroll
            for (int ct = 0; ct < 8; ct++) {
                float p = __expf(s[ct][r] - mnew);
                rsum += p;
                Ps[prow + r][ct * 16 + (lane & 15)] = (bf16)p;
            }
            #pragma unroll
            for (int d2 = 1; d2 < 16; d2 <<= 1) rsum += __shfl_xor(rsum, d2, 64);
            l_r[r] = l_r[r] * scale + rsum;
            #pragma unroll
            for (int dt = 0; dt < 4; dt++) o_[dt][r] *= scale;
        }

        // O += P @ V   (P: 16x128, V: 128x64)
        #pragma unroll
        for (int kf = 0; kf < 4; kf++) {
            bf16x8 pf = *(const bf16x8*)&Ps[w * 16 + (lane & 15)][kf * 32 + kq];
            #pragma unroll
            for (int dt = 0; dt < 4; dt++) {
                bf16x8 vf = *(const bf16x8*)&Vs[dt * 16 + (lane & 15)][kf * 32 + kq];
                o_[dt] = MFMA16(pf, vf, o_[dt]);
            }
        }
    }

    // write O as (b, n, h*64+d) bf16
    const int b = bh >> 4, h = bh & 15;
    #pragma unroll
    for (int dt = 0; dt < 4; dt++) {
        #pragma unroll
        for (int r = 0; r < 4; r++) {
            int ntok = qt * 64 + w * 16 + (lane >> 4) * 4 + r;
            float val = o_[dt][r] / l_r[r];
            O[((size_t)b * TOK + ntok) * DIM + h * HD + dt * 16 + (lane & 15)] = (bf16)val;
        }
    }
}

// ---------------------------------------------------------------------------
// Kernel 3: out = O @ Wo.T + bo (fp32 out). O already bf16; Wo 2-term split.
// ---------------------------------------------------------------------------
__global__ __launch_bounds__(256) void k_out(
    const bf16* __restrict__ O, const float* __restrict__ Wo,
    const float* __restrict__ bo, float* __restrict__ out)
{
    __shared__ bf16 As[128][40];
    __shared__ bf16 Bh[128][40];
    __shared__ bf16 Bl[128][40];

    const int nt = blockIdx.x;   // 0..7
    const int mt = blockIdx.y;   // 0..31
    const int t = threadIdx.x;
    const int lane = t & 63;
    const int w = t >> 6;
    const int wr = w >> 1, wc = w & 1;

    f32x4 zero = {0.f, 0.f, 0.f, 0.f};
    f32x4 acc[4][4];
    #pragma unroll
    for (int m = 0; m < 4; m++)
        #pragma unroll
        for (int n = 0; n < 4; n++) acc[m][n] = zero;

    const int sr = t >> 1, sc = (t & 1) * 16;
    const bf16*  os = O  + (size_t)(mt * 128 + sr) * DIM + sc;
    const float* ws = Wo + (size_t)(nt * 128 + sr) * DIM + sc;

    for (int k0 = 0; k0 < DIM; k0 += 32) {
        __syncthreads();
        *(bf16x8*)&As[sr][sc]     = *(const bf16x8*)(os + k0);
        *(bf16x8*)&As[sr][sc + 8] = *(const bf16x8*)(os + k0 + 8);
        #pragma unroll
        for (int i = 0; i < 4; i++) {
            f32x4 vw = *(const f32x4*)(ws + k0 + i * 4);
            bf16x4 wh, wl;
            #pragma unroll
            for (int j = 0; j < 4; j++) {
                bf16 g = (bf16)vw[j]; wh[j] = g; wl[j] = (bf16)(vw[j] - (float)g);
            }
            *(bf16x4*)&Bh[sr][sc + i * 4] = wh;
            *(bf16x4*)&Bl[sr][sc + i * 4] = wl;
        }
        __syncthreads();

        const int kq = (lane >> 4) * 8;
        bf16x8 a[4], bh[4], bl[4];
        #pragma unroll
        for (int m = 0; m < 4; m++) {
            int r = wr * 64 + m * 16 + (lane & 15);
            a[m] = *(const bf16x8*)&As[r][kq];
        }
        #pragma unroll
        for (int n = 0; n < 4; n++) {
            int r = wc * 64 + n * 16 + (lane & 15);
            bh[n] = *(const bf16x8*)&Bh[r][kq];
            bl[n] = *(const bf16x8*)&Bl[r][kq];
        }
        #pragma unroll
        for (int m = 0; m < 4; m++)
            #pragma unroll
            for (int n = 0; n < 4; n++) {
                acc[m][n] = MFMA16(a[m], bh[n], acc[m][n]);
                acc[m][n] = MFMA16(a[m], bl[n], acc[m][n]);
            }
    }

    #pragma unroll
    for (int m = 0; m < 4; m++) {
        #pragma unroll
        for (int n = 0; n < 4; n++) {
            const int grow0 = mt * 128 + wr * 64 + m * 16 + (lane >> 4) * 4;
            const int gcol  = nt * 128 + wc * 64 + n * 16 + (lane & 15);
            const float bias = bo[gcol];
            #pragma unroll
            for (int r = 0; r < 4; r++)
                out[(size_t)(grow0 + r) * DIM + gcol] = acc[m][n][r] + bias;
        }
    }
}

// ---------------------------------------------------------------------------
extern "C" void kernel_launch(void* const* d_in, const int* in_sizes, int n_in,
                              void* d_out, int out_size, void* d_ws, size_t ws_size,
                              hipStream_t stream)
{
    const float* x    = (const float*)d_in[0];
    const float* cosT = (const float*)d_in[1];
    const float* sinT = (const float*)d_in[2];
    const float* Wq   = (const float*)d_in[3];
    const float* Wk   = (const float*)d_in[4];
    const float* Wv   = (const float*)d_in[5];
    const float* Wo   = (const float*)d_in[6];
    const float* bo   = (const float*)d_in[7];
    float* out = (float*)d_out;

    const size_t NELEM = (size_t)MTOT * DIM;   // 4M elements per buffer
    bf16* qw = (bf16*)d_ws;
    bf16* kw = qw + NELEM;
    bf16* vw = kw + NELEM;
    bf16* ow = vw + NELEM;

    dim3 blk(256);
    k_qkv<<<dim3(8, 32, 3), blk, 0, stream>>>(x, Wq, Wk, Wv, cosT, sinT, qw, kw, vw);
    k_attn<<<dim3(16, 64), blk, 0, stream>>>(qw, kw, vw, ow);
    k_out<<<dim3(8, 32), blk, 0, stream>>>(ow, Wo, bo, out);
}